// Round 7
// baseline (211.858 us; speedup 1.0000x reference)
//
#include <hip/hip_runtime.h>
#include <hip/hip_bf16.h>

// PrototypeConsistentLearning: loss = mean(-pos + lse_neg), new_protos = serial EMA.
// B=8192, D=512, K=16384, T=0.5, momentum=0.9.
// R13: R12's data placement (A in regs: afr[4][4] loaded once from global; B in
// row-major XOR-swizzled LDS, triple-buffered, contiguous gl_lds staging, ONE
// barrier + counted vmcnt per step) but WITHOUT R12's lgkmcnt(0)+sched_barrier
// pins. R12's pins lockstepped all 8 waves (burst-read -> full-latency wait ->
// burst-MFMA), serializing the LDS and MFMA pipes: measured 4073 cy/step =
// sum of serialized pipes. Unpinned, the compiler emits fine-grained lgkmcnt(N)
// and waves slip -> LDS (~1280 cy/step) overlaps MFMA (1106 cy/step).
// bf read as two named halves around the first MFMA cluster (peak regs ~240
// < 256 cap). Plus bijective XCD remap: wgl=bx+64*by, by'=(wgl&7)>>1,
// bx'=(wgl>>3)*2+(wgl&1) -- each XCD-pair owns one K-split so its 2 MB proq
// slice is L2-resident (FETCH 35 MB vs 12 MB ideal = cross-XCD L2 thrash).
// Same x16 e4m3 quantization + XOR granule swizzle for B (stored slot =
// granule ^ (row&7); inverse applied at the global source). pos/EMA exact fp32.

#define B_N 8192
#define D_N 512
#define K_N 16384
#define INV_T 2.0f
#define MOM 0.9f

#define BM 128          // A rows per block (in registers)
#define BKF 128         // K bytes per chunk
#define BTR 256         // B rows per tile
#define KSPLIT 4        // each block covers K_N/KSPLIT = 4096 B-rows
#define NTILE 16        // B tiles per block (4096 / BTR)
#define BUFB 32768      // bytes per B buffer
#define CAP 64

typedef __attribute__((ext_vector_type(8))) int intx8;
typedef __attribute__((ext_vector_type(4))) float floatx4;

__device__ __forceinline__ void gl_lds16(const void* g, void* lds) {
    __builtin_amdgcn_global_load_lds(
        (const __attribute__((address_space(1))) void*)g,
        (__attribute__((address_space(3))) void*)lds, 16, 0, 0);
}

__device__ __forceinline__ intx8 frag2(const unsigned char* rp, int o0, int o1) {
    intx8 v;
    ((int4*)&v)[0] = *(const int4*)(rp + o0);
    ((int4*)&v)[1] = *(const int4*)(rp + o1);
    return v;
}

__device__ __forceinline__ floatx4 mxfma(intx8 a, intx8 b, floatx4 c) {
    return __builtin_amdgcn_mfma_scale_f32_16x16x128_f8f6f4(a, b, c, 0, 0, 0,
                                                            0x7F7F7F7F, 0, 0x7F7F7F7F);
}

// ---- normalize rows (fp32) -> e4m3 fp8 scaled by 16; also zero rowsum/out[0]. ----
__global__ void norm_kernel(const float* __restrict__ emb, const float* __restrict__ pro,
                            unsigned char* __restrict__ embq, unsigned char* __restrict__ proq,
                            float* __restrict__ rowsum, float* __restrict__ out) {
    if (blockIdx.x < 32) rowsum[blockIdx.x * 256 + threadIdx.x] = 0.0f;
    if (blockIdx.x == 32 && threadIdx.x == 0) out[0] = 0.0f;
    int row = blockIdx.x * 4 + (threadIdx.x >> 6);
    int lane = threadIdx.x & 63;
    const float* x;
    unsigned char* o;
    if (row < B_N) {
        x = emb + (size_t)row * D_N;
        o = embq + (size_t)row * D_N;
    } else {
        x = pro + (size_t)(row - B_N) * D_N;
        o = proq + (size_t)(row - B_N) * D_N;
    }
    const float4* xp = (const float4*)(x + lane * 8);
    float4 v0 = xp[0];
    float4 v1 = xp[1];
    float ss = v0.x * v0.x + v0.y * v0.y + v0.z * v0.z + v0.w * v0.w +
               v1.x * v1.x + v1.y * v1.y + v1.z * v1.z + v1.w * v1.w;
    #pragma unroll
    for (int of = 32; of; of >>= 1) ss += __shfl_xor(ss, of);
    float sc = 16.0f / fmaxf(sqrtf(ss), 1e-12f);  // x16: e4m3 keeps full mantissa range
    int w0 = 0, w1 = 0;
    w0 = __builtin_amdgcn_cvt_pk_fp8_f32(v0.x * sc, v0.y * sc, w0, false);
    w0 = __builtin_amdgcn_cvt_pk_fp8_f32(v0.z * sc, v0.w * sc, w0, true);
    w1 = __builtin_amdgcn_cvt_pk_fp8_f32(v1.x * sc, v1.y * sc, w1, false);
    w1 = __builtin_amdgcn_cvt_pk_fp8_f32(v1.z * sc, v1.w * sc, w1, true);
    int2 st = {w0, w1};
    *(int2*)(o + lane * 8) = st;
}

// ---- pos[b] = 2 * dot(emb[b],pro[c]) / (|emb[b]| |pro[c]|), pure fp32 (exact). ----
__global__ void pos_kernel(const float* __restrict__ emb, const float* __restrict__ pro,
                           const int* __restrict__ cid, float* __restrict__ rowpos) {
    int b = blockIdx.x * 4 + (threadIdx.x >> 6);
    int lane = threadIdx.x & 63;
    int c = cid[b];
    const float4* ep = (const float4*)(emb + (size_t)b * D_N + lane * 8);
    const float4* pp = (const float4*)(pro + (size_t)c * D_N + lane * 8);
    float4 e0 = ep[0], e1 = ep[1], p0 = pp[0], p1 = pp[1];
    float dp = e0.x * p0.x + e0.y * p0.y + e0.z * p0.z + e0.w * p0.w +
               e1.x * p1.x + e1.y * p1.y + e1.z * p1.z + e1.w * p1.w;
    float ee = e0.x * e0.x + e0.y * e0.y + e0.z * e0.z + e0.w * e0.w +
               e1.x * e1.x + e1.y * e1.y + e1.z * e1.z + e1.w * e1.w;
    float qq = p0.x * p0.x + p0.y * p0.y + p0.z * p0.z + p0.w * p0.w +
               p1.x * p1.x + p1.y * p1.y + p1.z * p1.z + p1.w * p1.w;
    #pragma unroll
    for (int o = 32; o; o >>= 1) {
        dp += __shfl_xor(dp, o);
        ee += __shfl_xor(ee, o);
        qq += __shfl_xor(qq, o);
    }
    if (lane == 0)
        rowpos[b] = INV_T * dp / (fmaxf(sqrtf(ee), 1e-12f) * fmaxf(sqrtf(qq), 1e-12f));
}

// One chunk-step. CH = literal 0..3; afr indexed only by literal CH (rule #20).
// No lgkm/sched pins: compiler emits fine-grained waits, waves slip freely.
#define FSTEP(CH)                                                                     \
    do {                                                                              \
        const int cc = tt * 4 + (CH);                                                 \
        const int bW = bR >= BUFB ? bR - BUFB : bR + 2 * BUFB;                        \
        if (tt < NTILE - 1 || (CH) < 2) {                                             \
            /* stage chunk cc+2: tile (cc+2)>>2, D-chunk (CH+2)&3 */                  \
            const unsigned char* s = bS + (size_t)(((cc + 2) >> 2) * BTR) * D_N +     \
                                     ((((CH) + 2) & 3) << 7);                         \
            unsigned char* d = Bs + bW + ldsW;                                        \
            _Pragma("unroll")                                                         \
            for (int p = 0; p < 4; p++)                                               \
                gl_lds16(s + (size_t)p * 64 * D_N, d + p * 8192);                     \
        }                                                                             \
        const unsigned char* rb = Bs + bR + (wn * 64 + lcol) * BKF;                   \
        intx8 bfA0 = frag2(rb + 0 * (16 * BKF), fsw0, fsw1);                          \
        intx8 bfA1 = frag2(rb + 1 * (16 * BKF), fsw0, fsw1);                          \
        __builtin_amdgcn_s_setprio(1);                                                \
        _Pragma("unroll")                                                             \
        for (int i = 0; i < 4; i++) {                                                 \
            acc[i][0] = mxfma(afr[(CH)][i], bfA0, acc[i][0]);                         \
            acc[i][1] = mxfma(afr[(CH)][i], bfA1, acc[i][1]);                         \
        }                                                                             \
        __builtin_amdgcn_s_setprio(0);                                                \
        intx8 bfB0 = frag2(rb + 2 * (16 * BKF), fsw0, fsw1);                          \
        intx8 bfB1 = frag2(rb + 3 * (16 * BKF), fsw0, fsw1);                          \
        __builtin_amdgcn_s_setprio(1);                                                \
        _Pragma("unroll")                                                             \
        for (int i = 0; i < 4; i++) {                                                 \
            acc[i][2] = mxfma(afr[(CH)][i], bfB0, acc[i][2]);                         \
            acc[i][3] = mxfma(afr[(CH)][i], bfB1, acc[i][3]);                         \
        }                                                                             \
        __builtin_amdgcn_s_setprio(0);                                                \
        if ((CH) == 3) { /* K complete: exp + accumulate, reset acc (VALU-only) */    \
            _Pragma("unroll")                                                         \
            for (int i = 0; i < 4; i++)                                               \
                _Pragma("unroll")                                                     \
                for (int j = 0; j < 4; j++)                                           \
                    _Pragma("unroll")                                                 \
                    for (int r = 0; r < 4; r++) {                                     \
                        rs[i * 4 + r] += __expf(acc[i][j][r] * (INV_T / 256.0f));     \
                        acc[i][j][r] = 0.0f;                                          \
                    }                                                                 \
        }                                                                             \
        if (tt < NTILE - 1 || (CH) < 2)                                               \
            asm volatile("s_waitcnt vmcnt(4)" ::: "memory");                          \
        else                                                                          \
            asm volatile("s_waitcnt vmcnt(0)" ::: "memory");                          \
        __builtin_amdgcn_s_barrier();                                                 \
        bR = bR == 2 * BUFB ? 0 : bR + BUFB;                                          \
    } while (0)

// ---- flash GEMM (MX-fp8, A in regs, B triple-buffered LDS, 1 barrier/step):
//      rowsum[b] += sum_k exp(2*dot(emb_n[b], proto_n[k]))  ----
__global__ __launch_bounds__(512, 2) void flash_kernel(const unsigned char* __restrict__ embq,
                                                       const unsigned char* __restrict__ proq,
                                                       float* __restrict__ rowsum_g) {
    __shared__ __align__(16) unsigned char Bs[3 * BUFB];  // 96 KB, triple-buffered
    const int t = threadIdx.x;
    const int w = t >> 6, lane = t & 63;
    const int quad = lane >> 4, lcol = lane & 15;
    const int wm = w >> 2, wn = w & 3;  // 2M x 4N wave grid; per-wave C = 64x64

    // Bijective XCD remap: consecutive linear ids round-robin XCDs; give each
    // XCD-pair one K-split so its 2 MB proq slice stays L2-resident.
    const int wgl = blockIdx.x + (int)gridDim.x * blockIdx.y;  // 0..255
    const int byp = (wgl & 7) >> 1;                            // 0..3 K-split
    const int bxp = ((wgl >> 3) << 1) + (wgl & 1);             // 0..63 row-block
    const int rowBase = bxp * BM;
    const int kb = byp * (K_N / KSPLIT);

    // B fragment granule offsets: logical granules quad*2, quad*2+1 of a 128-B
    // chunk-row; stored slot = granule ^ (row&7); frag rows have row&7 == lcol&7.
    const int fsw0 = (((quad << 1) | 0) ^ (lcol & 7)) << 4;
    const int fsw1 = (((quad << 1) | 1) ^ (lcol & 7)) << 4;
    const int ldsW = w * 1024;

    // B staging: pass p writes rows p*64 + w*8 + (lane>>3) of the chunk; stored
    // slot lane&7 -> source granule (lane&7)^((lane>>3)&7).
    const unsigned char* bS = proq + (size_t)(kb + w * 8 + (lane >> 3)) * D_N +
                              (((lane & 7) ^ ((lane >> 3) & 7)) << 4);

    floatx4 acc[4][4];
    float rs[16];
    #pragma unroll
    for (int i = 0; i < 4; i++)
        #pragma unroll
        for (int j = 0; j < 4; j++) {
            floatx4 z = {0.0f, 0.0f, 0.0f, 0.0f};
            acc[i][j] = z;
        }
    #pragma unroll
    for (int i = 0; i < 16; i++) rs[i] = 0.0f;

    // ---- prologue: A frags direct from global (32 dwordx4 -> 128 VGPR), then
    //      stage B chunk0 -> buf0, chunk1 -> buf1. vmcnt(4): A+B0 done, B1 out. ----
    intx8 afr[4][4];
    {
        const unsigned char* aBase =
            embq + (size_t)(rowBase + wm * 64 + lcol) * D_N + quad * 32;
        #pragma unroll
        for (int ch = 0; ch < 4; ch++)
            #pragma unroll
            for (int i = 0; i < 4; i++) {
                const unsigned char* p = aBase + (size_t)i * (16 * D_N) + (ch << 7);
                ((int4*)&afr[ch][i])[0] = *(const int4*)(p);
                ((int4*)&afr[ch][i])[1] = *(const int4*)(p + 16);
            }
    }
    #pragma unroll
    for (int p = 0; p < 4; p++)
        gl_lds16(bS + (size_t)p * 64 * D_N, Bs + p * 8192 + ldsW);
    #pragma unroll
    for (int p = 0; p < 4; p++)
        gl_lds16(bS + (size_t)p * 64 * D_N + BKF, Bs + BUFB + p * 8192 + ldsW);
    asm volatile("s_waitcnt vmcnt(4)" ::: "memory");
    __builtin_amdgcn_s_barrier();

    int bR = 0;  // read-buffer byte offset (wave-uniform scalar)
    for (int tt = 0; tt < NTILE; tt++) {
        FSTEP(0);
        FSTEP(1);
        FSTEP(2);
        FSTEP(3);
    }

    // C/D layout: col=lane&15, row=quad*4+r. rs[i*4+r] holds the partial sum for
    // row wm*64+i*16+quad*4+r over this wave's 64 columns x this lcol; reduce
    // over the 16 lcol lanes (stays within the quad), then one atomic per row.
    #pragma unroll
    for (int i = 0; i < 16; i++) {
        #pragma unroll
        for (int o = 1; o < 16; o <<= 1) rs[i] += __shfl_xor(rs[i], o);
    }
    if (lcol == 0) {
        #pragma unroll
        for (int i = 0; i < 4; i++)
            #pragma unroll
            for (int r = 0; r < 4; r++)
                atomicAdd(&rowsum_g[rowBase + wm * 64 + i * 16 + quad * 4 + r],
                          rs[i * 4 + r]);
    }
}

// ---- loss partial: 32 blocks, atomicAdd into out[0]; also zero cnt for EMA. ----
__global__ void loss_kernel(const float* __restrict__ rowsum, const float* __restrict__ rowpos,
                            float* __restrict__ out, int* __restrict__ cnt) {
    __shared__ float red[256];
    int t = threadIdx.x;
    int b = blockIdx.x * 256 + t;
    cnt[b * 2] = 0;
    cnt[b * 2 + 1] = 0;
    float p = rowpos[b];
    red[t] = logf(rowsum[b] - __expf(p)) - p;
    __syncthreads();
    for (int o = 128; o; o >>= 1) {
        if (t < o) red[t] += red[t + o];
        __syncthreads();
    }
    if (t == 0) atomicAdd(out, red[0] * (1.0f / (float)B_N));
}

// ---- EMA phase 1: bucket occurrence indices per cluster. ----
__global__ void ema_count(const int* __restrict__ cid, int* __restrict__ cnt,
                          int* __restrict__ bucket) {
    int b = blockIdx.x * 256 + threadIdx.x;
    int c = cid[b];
    int slot = atomicAdd(&cnt[c], 1);
    if (slot < CAP) bucket[c * CAP + slot] = b;
}

// ---- EMA phase 2: one wave per cluster, replay occurrences in ascending b. ----
__global__ void ema_apply(const float* __restrict__ emb, const float* __restrict__ pro,
                          const int* __restrict__ cnt, const int* __restrict__ bucket,
                          float* __restrict__ outp) {
    int k = blockIdx.x * 4 + (threadIdx.x >> 6);
    int lane = threadIdx.x & 63;
    int n = cnt[k];
    n = n < CAP ? n : CAP;
    const float4* pp = (const float4*)(pro + (size_t)k * D_N + lane * 8);
    float4 a0 = pp[0], a1 = pp[1];
    int myb = (lane < n) ? bucket[k * CAP + lane] : 0x7fffffff;
    for (int i = 0; i < n; i++) {
        int m = myb;
        #pragma unroll
        for (int o = 1; o < 64; o <<= 1) {
            int v = __shfl_xor(m, o);
            m = v < m ? v : m;
        }
        const float4* ep = (const float4*)(emb + (size_t)m * D_N + lane * 8);
        float4 e0 = ep[0], e1 = ep[1];
        a0.x = MOM * a0.x + (1.0f - MOM) * e0.x;
        a0.y = MOM * a0.y + (1.0f - MOM) * e0.y;
        a0.z = MOM * a0.z + (1.0f - MOM) * e0.z;
        a0.w = MOM * a0.w + (1.0f - MOM) * e0.w;
        a1.x = MOM * a1.x + (1.0f - MOM) * e1.x;
        a1.y = MOM * a1.y + (1.0f - MOM) * e1.y;
        a1.z = MOM * a1.z + (1.0f - MOM) * e1.z;
        a1.w = MOM * a1.w + (1.0f - MOM) * e1.w;
        if (myb == m) myb = 0x7fffffff;
    }
    float4* op = (float4*)(outp + (size_t)k * D_N + lane * 8);
    op[0] = a0;
    op[1] = a1;
}

extern "C" void kernel_launch(void* const* d_in, const int* in_sizes, int n_in,
                              void* d_out, int out_size, void* d_ws, size_t ws_size,
                              hipStream_t stream) {
    const float* emb = (const float*)d_in[0];
    const int* cid = (const int*)d_in[1];
    const float* pro = (const float*)d_in[2];
    float* out = (float*)d_out;

    char* ws = (char*)d_ws;
    unsigned char* embq = (unsigned char*)ws;                      // 4 MB fp8 [B,D]
    unsigned char* proq = (unsigned char*)(ws + 4194304);          // 8 MB fp8 [K,D]
    float* rowsum = (float*)(ws + 12582912);                       // [B]
    float* rowpos = (float*)(ws + 12615680);                       // [B]
    // EMA buckets alias the proq region — only touched after flash_kernel (stream
    // order): loss_kernel zeroes cnt, ema_count fills, ema_apply reads.
    int* cnt = (int*)(ws + 4194304);                               // [K]
    int* bucket = (int*)(ws + 4194304 + 65536);                    // [K, CAP]

    norm_kernel<<<(B_N + K_N) / 4, 256, 0, stream>>>(emb, pro, embq, proq, rowsum, out);
    pos_kernel<<<B_N / 4, 256, 0, stream>>>(emb, pro, cid, rowpos);
    flash_kernel<<<dim3(B_N / BM, KSPLIT), 512, 0, stream>>>(embq, proq, rowsum);
    loss_kernel<<<B_N / 256, 256, 0, stream>>>(rowsum, rowpos, out, cnt);
    ema_count<<<B_N / 256, 256, 0, stream>>>(cid, cnt, bucket);
    ema_apply<<<K_N / 4, 256, 0, stream>>>(emb, pro, cnt, bucket, out + 1);
}

// Round 8
// 190.932 us; speedup vs baseline: 1.1096x; 1.1096x over previous
//
#include <hip/hip_runtime.h>
#include <hip/hip_bf16.h>

// PrototypeConsistentLearning: loss = mean(-pos + lse_neg), new_protos = serial EMA.
// B=8192, D=512, K=16384, T=0.5, momentum=0.9.
// R14: same data placement as R13 (A in regs afr[4][4] loaded once from global;
// B row-major XOR-swizzled LDS staged with contiguous gl_lds), but m97 geometry:
// 128^2 tile, 4 waves (2Mx2N), 256 threads, 32 KB LDS (2x16 KB dbuf), KSPLIT=8
// -> 512 blocks = 2 blocks/CU. R8-R13 all ran 1 block/CU (96-128 KB LDS): every
// barrier bubble (staging drain, first-frag latency, epilogue VALU) stalled the
// whole CU -> 3600-4100 cy/step regardless of schedule (R11 89us / R12 108 /
// R13 98, MfmaUtil 25-31%). With 2 independent blocks/CU the other block's
// MFMAs fill those bubbles (the proven m97 mechanism: implicit wave-level
// overlap beats source-level pipelining). Sync = ONE __syncthreads per step
// (its vmcnt drain is the m97 stall, now hidden). XCD remap: wgid%8 = K-split
// -> each XCD's 1 MB proq slice is L2-resident (R13: FETCH 35->16.5 MB).
// Per-wave regs identical to R13 (acc 64 AGPR + afr 128 + bf 16-reg transients,
// VGPR_Count 128, no spill). Same x16 e4m3 quantization + XOR granule swizzle
// (stored slot = granule ^ (row&7); inverse at the global source). pos/EMA fp32.

#define B_N 8192
#define D_N 512
#define K_N 16384
#define INV_T 2.0f
#define MOM 0.9f

#define BM 128          // A rows per block (in registers)
#define BKF 128         // K bytes per chunk
#define BTR 128         // B rows per tile
#define KSPLIT 8        // each block covers K_N/KSPLIT = 2048 B-rows
#define NTILE 16        // B tiles per block (2048 / BTR)
#define BUFB 16384      // bytes per B buffer
#define CAP 64

typedef __attribute__((ext_vector_type(8))) int intx8;
typedef __attribute__((ext_vector_type(4))) float floatx4;

__device__ __forceinline__ void gl_lds16(const void* g, void* lds) {
    __builtin_amdgcn_global_load_lds(
        (const __attribute__((address_space(1))) void*)g,
        (__attribute__((address_space(3))) void*)lds, 16, 0, 0);
}

__device__ __forceinline__ intx8 frag2(const unsigned char* rp, int o0, int o1) {
    intx8 v;
    ((int4*)&v)[0] = *(const int4*)(rp + o0);
    ((int4*)&v)[1] = *(const int4*)(rp + o1);
    return v;
}

__device__ __forceinline__ floatx4 mxfma(intx8 a, intx8 b, floatx4 c) {
    return __builtin_amdgcn_mfma_scale_f32_16x16x128_f8f6f4(a, b, c, 0, 0, 0,
                                                            0x7F7F7F7F, 0, 0x7F7F7F7F);
}

// ---- normalize rows (fp32) -> e4m3 fp8 scaled by 16; also zero rowsum/out[0]. ----
__global__ void norm_kernel(const float* __restrict__ emb, const float* __restrict__ pro,
                            unsigned char* __restrict__ embq, unsigned char* __restrict__ proq,
                            float* __restrict__ rowsum, float* __restrict__ out) {
    if (blockIdx.x < 32) rowsum[blockIdx.x * 256 + threadIdx.x] = 0.0f;
    if (blockIdx.x == 32 && threadIdx.x == 0) out[0] = 0.0f;
    int row = blockIdx.x * 4 + (threadIdx.x >> 6);
    int lane = threadIdx.x & 63;
    const float* x;
    unsigned char* o;
    if (row < B_N) {
        x = emb + (size_t)row * D_N;
        o = embq + (size_t)row * D_N;
    } else {
        x = pro + (size_t)(row - B_N) * D_N;
        o = proq + (size_t)(row - B_N) * D_N;
    }
    const float4* xp = (const float4*)(x + lane * 8);
    float4 v0 = xp[0];
    float4 v1 = xp[1];
    float ss = v0.x * v0.x + v0.y * v0.y + v0.z * v0.z + v0.w * v0.w +
               v1.x * v1.x + v1.y * v1.y + v1.z * v1.z + v1.w * v1.w;
    #pragma unroll
    for (int of = 32; of; of >>= 1) ss += __shfl_xor(ss, of);
    float sc = 16.0f / fmaxf(sqrtf(ss), 1e-12f);  // x16: e4m3 keeps full mantissa range
    int w0 = 0, w1 = 0;
    w0 = __builtin_amdgcn_cvt_pk_fp8_f32(v0.x * sc, v0.y * sc, w0, false);
    w0 = __builtin_amdgcn_cvt_pk_fp8_f32(v0.z * sc, v0.w * sc, w0, true);
    w1 = __builtin_amdgcn_cvt_pk_fp8_f32(v1.x * sc, v1.y * sc, w1, false);
    w1 = __builtin_amdgcn_cvt_pk_fp8_f32(v1.z * sc, v1.w * sc, w1, true);
    int2 st = {w0, w1};
    *(int2*)(o + lane * 8) = st;
}

// ---- pos[b] = 2 * dot(emb[b],pro[c]) / (|emb[b]| |pro[c]|), pure fp32 (exact). ----
__global__ void pos_kernel(const float* __restrict__ emb, const float* __restrict__ pro,
                           const int* __restrict__ cid, float* __restrict__ rowpos) {
    int b = blockIdx.x * 4 + (threadIdx.x >> 6);
    int lane = threadIdx.x & 63;
    int c = cid[b];
    const float4* ep = (const float4*)(emb + (size_t)b * D_N + lane * 8);
    const float4* pp = (const float4*)(pro + (size_t)c * D_N + lane * 8);
    float4 e0 = ep[0], e1 = ep[1], p0 = pp[0], p1 = pp[1];
    float dp = e0.x * p0.x + e0.y * p0.y + e0.z * p0.z + e0.w * p0.w +
               e1.x * p1.x + e1.y * p1.y + e1.z * p1.z + e1.w * p1.w;
    float ee = e0.x * e0.x + e0.y * e0.y + e0.z * e0.z + e0.w * e0.w +
               e1.x * e1.x + e1.y * e1.y + e1.z * e1.z + e1.w * e1.w;
    float qq = p0.x * p0.x + p0.y * p0.y + p0.z * p0.z + p0.w * p0.w +
               p1.x * p1.x + p1.y * p1.y + p1.z * p1.z + p1.w * p1.w;
    #pragma unroll
    for (int o = 32; o; o >>= 1) {
        dp += __shfl_xor(dp, o);
        ee += __shfl_xor(ee, o);
        qq += __shfl_xor(qq, o);
    }
    if (lane == 0)
        rowpos[b] = INV_T * dp / (fmaxf(sqrtf(ee), 1e-12f) * fmaxf(sqrtf(qq), 1e-12f));
}

// One chunk-step. CH = literal 0..3; afr indexed only by literal CH (rule #20).
// One __syncthreads per step; its implicit vmcnt drain is hidden by the other
// co-resident block on this CU (m97 mechanism).
#define FSTEP(CH)                                                                     \
    do {                                                                              \
        const int cc = tt * 4 + (CH);                                                 \
        if (cc + 1 < NTILE * 4) { /* stage chunk cc+1 into the other buffer */        \
            const unsigned char* s = bS + (size_t)(((cc + 1) >> 2) * BTR) * D_N +     \
                                     ((((CH) + 1) & 3) << 7);                         \
            unsigned char* d = Bs + ((cc + 1) & 1) * BUFB + w * 1024;                 \
            _Pragma("unroll")                                                         \
            for (int p = 0; p < 4; p++)                                               \
                gl_lds16(s + (size_t)p * 32 * D_N, d + p * 4096);                     \
        }                                                                             \
        const unsigned char* rb = Bs + ((cc)&1) * BUFB + (wn * 64 + lcol) * BKF;      \
        intx8 bfA0 = frag2(rb + 0 * (16 * BKF), fsw0, fsw1);                          \
        intx8 bfA1 = frag2(rb + 1 * (16 * BKF), fsw0, fsw1);                          \
        __builtin_amdgcn_s_setprio(1);                                                \
        _Pragma("unroll")                                                             \
        for (int i = 0; i < 4; i++) {                                                 \
            acc[i][0] = mxfma(afr[(CH)][i], bfA0, acc[i][0]);                         \
            acc[i][1] = mxfma(afr[(CH)][i], bfA1, acc[i][1]);                         \
        }                                                                             \
        __builtin_amdgcn_s_setprio(0);                                                \
        intx8 bfB0 = frag2(rb + 2 * (16 * BKF), fsw0, fsw1);                          \
        intx8 bfB1 = frag2(rb + 3 * (16 * BKF), fsw0, fsw1);                          \
        __builtin_amdgcn_s_setprio(1);                                                \
        _Pragma("unroll")                                                             \
        for (int i = 0; i < 4; i++) {                                                 \
            acc[i][2] = mxfma(afr[(CH)][i], bfB0, acc[i][2]);                         \
            acc[i][3] = mxfma(afr[(CH)][i], bfB1, acc[i][3]);                         \
        }                                                                             \
        __builtin_amdgcn_s_setprio(0);                                                \
        if ((CH) == 3) { /* K complete: exp + accumulate, reset acc (VALU-only) */    \
            _Pragma("unroll")                                                         \
            for (int i = 0; i < 4; i++)                                               \
                _Pragma("unroll")                                                     \
                for (int j = 0; j < 4; j++)                                           \
                    _Pragma("unroll")                                                 \
                    for (int r = 0; r < 4; r++) {                                     \
                        rs[i * 4 + r] += __expf(acc[i][j][r] * (INV_T / 256.0f));     \
                        acc[i][j][r] = 0.0f;                                          \
                    }                                                                 \
        }                                                                             \
        __syncthreads(); /* stage cc+1 done + all waves finished reading buf cc&1 */  \
    } while (0)

// ---- flash GEMM (MX-fp8, A in regs, B 2x16KB LDS dbuf, 2 blocks/CU):
//      rowsum[b] += sum_k exp(2*dot(emb_n[b], proto_n[k]))  ----
__global__ __launch_bounds__(256, 2) void flash_kernel(const unsigned char* __restrict__ embq,
                                                       const unsigned char* __restrict__ proq,
                                                       float* __restrict__ rowsum_g) {
    __shared__ __align__(16) unsigned char Bs[2 * BUFB];  // 32 KB, double-buffered
    const int t = threadIdx.x;
    const int w = t >> 6, lane = t & 63;
    const int quad = lane >> 4, lcol = lane & 15;
    const int wm = w >> 1, wn = w & 1;  // 2M x 2N wave grid; per-wave C = 64x64

    // XCD-pinned K-split: dispatch round-robins wgid%8 across XCDs, so K-split
    // ks = wgid%8 stays on one XCD -> its 1 MB proq slice is L2-resident.
    const int wgl = blockIdx.x;          // 0..511
    const int ks = wgl & 7;              // K-split 0..7
    const int bxp = wgl >> 3;            // row-block 0..63
    const int rowBase = bxp * BM;
    const int kb = ks * (K_N / KSPLIT);

    // B fragment granule offsets: logical granules quad*2, quad*2+1 of a 128-B
    // chunk-row; stored slot = granule ^ (row&7); frag rows have row&7 == lcol&7.
    const int fsw0 = (((quad << 1) | 0) ^ (lcol & 7)) << 4;
    const int fsw1 = (((quad << 1) | 1) ^ (lcol & 7)) << 4;

    // B staging: pass p writes rows p*32 + w*8 + (lane>>3) of the chunk; stored
    // slot lane&7 -> source granule (lane&7)^((lane>>3)&7).
    const unsigned char* bS = proq + (size_t)(kb + w * 8 + (lane >> 3)) * D_N +
                              (((lane & 7) ^ ((lane >> 3) & 7)) << 4);

    floatx4 acc[4][4];
    float rs[16];
    #pragma unroll
    for (int i = 0; i < 4; i++)
        #pragma unroll
        for (int j = 0; j < 4; j++) {
            floatx4 z = {0.0f, 0.0f, 0.0f, 0.0f};
            acc[i][j] = z;
        }
    #pragma unroll
    for (int i = 0; i < 16; i++) rs[i] = 0.0f;

    // ---- prologue: A frags direct from global (32 dwordx4 -> 128 VGPR), then
    //      stage B chunk0 -> buf0; __syncthreads drains it. ----
    intx8 afr[4][4];
    {
        const unsigned char* aBase =
            embq + (size_t)(rowBase + wm * 64 + lcol) * D_N + quad * 32;
        #pragma unroll
        for (int ch = 0; ch < 4; ch++)
            #pragma unroll
            for (int i = 0; i < 4; i++) {
                const unsigned char* p = aBase + (size_t)i * (16 * D_N) + (ch << 7);
                ((int4*)&afr[ch][i])[0] = *(const int4*)(p);
                ((int4*)&afr[ch][i])[1] = *(const int4*)(p + 16);
            }
    }
    #pragma unroll
    for (int p = 0; p < 4; p++)
        gl_lds16(bS + (size_t)p * 32 * D_N, Bs + p * 4096 + w * 1024);
    __syncthreads();

    for (int tt = 0; tt < NTILE; tt++) {
        FSTEP(0);
        FSTEP(1);
        FSTEP(2);
        FSTEP(3);
    }

    // C/D layout: col=lane&15, row=quad*4+r. rs[i*4+r] holds the partial sum for
    // row wm*64+i*16+quad*4+r over this wave's 64 columns x this lcol; reduce
    // over the 16 lcol lanes (stays within the quad), then one atomic per row.
    #pragma unroll
    for (int i = 0; i < 16; i++) {
        #pragma unroll
        for (int o = 1; o < 16; o <<= 1) rs[i] += __shfl_xor(rs[i], o);
    }
    if (lcol == 0) {
        #pragma unroll
        for (int i = 0; i < 4; i++)
            #pragma unroll
            for (int r = 0; r < 4; r++)
                atomicAdd(&rowsum_g[rowBase + wm * 64 + i * 16 + quad * 4 + r],
                          rs[i * 4 + r]);
    }
}

// ---- loss partial: 32 blocks, atomicAdd into out[0]; also zero cnt for EMA. ----
__global__ void loss_kernel(const float* __restrict__ rowsum, const float* __restrict__ rowpos,
                            float* __restrict__ out, int* __restrict__ cnt) {
    __shared__ float red[256];
    int t = threadIdx.x;
    int b = blockIdx.x * 256 + t;
    cnt[b * 2] = 0;
    cnt[b * 2 + 1] = 0;
    float p = rowpos[b];
    red[t] = logf(rowsum[b] - __expf(p)) - p;
    __syncthreads();
    for (int o = 128; o; o >>= 1) {
        if (t < o) red[t] += red[t + o];
        __syncthreads();
    }
    if (t == 0) atomicAdd(out, red[0] * (1.0f / (float)B_N));
}

// ---- EMA phase 1: bucket occurrence indices per cluster. ----
__global__ void ema_count(const int* __restrict__ cid, int* __restrict__ cnt,
                          int* __restrict__ bucket) {
    int b = blockIdx.x * 256 + threadIdx.x;
    int c = cid[b];
    int slot = atomicAdd(&cnt[c], 1);
    if (slot < CAP) bucket[c * CAP + slot] = b;
}

// ---- EMA phase 2: one wave per cluster, replay occurrences in ascending b. ----
__global__ void ema_apply(const float* __restrict__ emb, const float* __restrict__ pro,
                          const int* __restrict__ cnt, const int* __restrict__ bucket,
                          float* __restrict__ outp) {
    int k = blockIdx.x * 4 + (threadIdx.x >> 6);
    int lane = threadIdx.x & 63;
    int n = cnt[k];
    n = n < CAP ? n : CAP;
    const float4* pp = (const float4*)(pro + (size_t)k * D_N + lane * 8);
    float4 a0 = pp[0], a1 = pp[1];
    int myb = (lane < n) ? bucket[k * CAP + lane] : 0x7fffffff;
    for (int i = 0; i < n; i++) {
        int m = myb;
        #pragma unroll
        for (int o = 1; o < 64; o <<= 1) {
            int v = __shfl_xor(m, o);
            m = v < m ? v : m;
        }
        const float4* ep = (const float4*)(emb + (size_t)m * D_N + lane * 8);
        float4 e0 = ep[0], e1 = ep[1];
        a0.x = MOM * a0.x + (1.0f - MOM) * e0.x;
        a0.y = MOM * a0.y + (1.0f - MOM) * e0.y;
        a0.z = MOM * a0.z + (1.0f - MOM) * e0.z;
        a0.w = MOM * a0.w + (1.0f - MOM) * e0.w;
        a1.x = MOM * a1.x + (1.0f - MOM) * e1.x;
        a1.y = MOM * a1.y + (1.0f - MOM) * e1.y;
        a1.z = MOM * a1.z + (1.0f - MOM) * e1.z;
        a1.w = MOM * a1.w + (1.0f - MOM) * e1.w;
        if (myb == m) myb = 0x7fffffff;
    }
    float4* op = (float4*)(outp + (size_t)k * D_N + lane * 8);
    op[0] = a0;
    op[1] = a1;
}

extern "C" void kernel_launch(void* const* d_in, const int* in_sizes, int n_in,
                              void* d_out, int out_size, void* d_ws, size_t ws_size,
                              hipStream_t stream) {
    const float* emb = (const float*)d_in[0];
    const int* cid = (const int*)d_in[1];
    const float* pro = (const float*)d_in[2];
    float* out = (float*)d_out;

    char* ws = (char*)d_ws;
    unsigned char* embq = (unsigned char*)ws;                      // 4 MB fp8 [B,D]
    unsigned char* proq = (unsigned char*)(ws + 4194304);          // 8 MB fp8 [K,D]
    float* rowsum = (float*)(ws + 12582912);                       // [B]
    float* rowpos = (float*)(ws + 12615680);                       // [B]
    // EMA buckets alias the proq region — only touched after flash_kernel (stream
    // order): loss_kernel zeroes cnt, ema_count fills, ema_apply reads.
    int* cnt = (int*)(ws + 4194304);                               // [K]
    int* bucket = (int*)(ws + 4194304 + 65536);                    // [K, CAP]

    norm_kernel<<<(B_N + K_N) / 4, 256, 0, stream>>>(emb, pro, embq, proq, rowsum, out);
    pos_kernel<<<B_N / 4, 256, 0, stream>>>(emb, pro, cid, rowpos);
    flash_kernel<<<dim3(64 * KSPLIT), 256, 0, stream>>>(embq, proq, rowsum);
    loss_kernel<<<B_N / 256, 256, 0, stream>>>(rowsum, rowpos, out, cnt);
    ema_count<<<B_N / 256, 256, 0, stream>>>(cid, cnt, bucket);
    ema_apply<<<K_N / 4, 256, 0, stream>>>(emb, pro, cnt, bucket, out + 1);
}